// Round 6
// baseline (315.949 us; speedup 1.0000x reference)
//
#include <hip/hip_runtime.h>

// Problem dims
#define B_   256
#define N_   16000
#define C_   32
#define K_   64
#define T_   124
#define NJ   125      // 128-sample half-window block sums, j = 0..124
#define HID_ 50
#define OUT_ 10
#define TB_  1024     // snnB block size
#define CURS 52       // padded stride for cur/icur (float4-aligned)

typedef unsigned int u32;
typedef float v2f __attribute__((ext_vector_type(2)));
struct __align__(16) f2x2 { v2f lo, hi; };

// Exact single f32 ops (prevent fma contraction / reassociation).
__device__ __forceinline__ float fadd(float a, float b) { return __fadd_rn(a, b); }
__device__ __forceinline__ float fmul(float a, float b) { return __fmul_rn(a, b); }
__device__ __forceinline__ float fsub(float a, float b) { return __fsub_rn(a, b); }

// Packed f32 FMA: y.lo += a.lo*tap, y.hi += a.hi*tap, tap = slot k of pair-pair T,
// broadcast via VOP3P op_sel. T lives in SGPRs (s_load'd, wave-uniform): VOP3P
// permits one SGPR source. Each half is an IEEE f32 FMA == fmaf: bit-identical.
__device__ __forceinline__ void PKFMA(v2f& y, v2f a, const f2x2& T, int k) {
    switch (k) {
    case 0:  asm("v_pk_fma_f32 %0, %1, %2, %0 op_sel:[0,0,0] op_sel_hi:[1,0,1]"
                 : "+v"(y) : "v"(a), "s"(T.lo)); break;
    case 1:  asm("v_pk_fma_f32 %0, %1, %2, %0 op_sel:[0,1,0] op_sel_hi:[1,1,1]"
                 : "+v"(y) : "v"(a), "s"(T.lo)); break;
    case 2:  asm("v_pk_fma_f32 %0, %1, %2, %0 op_sel:[0,0,0] op_sel_hi:[1,0,1]"
                 : "+v"(y) : "v"(a), "s"(T.hi)); break;
    default: asm("v_pk_fma_f32 %0, %1, %2, %0 op_sel:[0,1,0] op_sel_hi:[1,1,1]"
                 : "+v"(y) : "v"(a), "s"(T.hi)); break;
    }
}

// ---------------------------------------------------------------------------
// Kernel A: conv (SAME pad_lo=31, correlation, sequential-k f32 FMA) + relu +
// numpy-pairwise 128-block sums -> Sg[b][c][j].
//
// ROUND-20: revert to the r4 two-pass structure (178 us; r5's 4-pass raised
// occupancy 40->64% but SLOWED to 190: kernel is FMA-pipe-bound, not
// latency-bound; v_pk_fma_f32 = 4cy/wave64, pipe floor ~109 us). New: tap
// double-buffer rotation — pair-unrolled q-loop alternates Ta/Tb roles so
// each tap quad is s_loaded exactly once (17 loads vs 33). Per-output
// accumulation order (q asc, e asc) unchanged: bit-exact.
// ---------------------------------------------------------------------------
__global__ __launch_bounds__(256, 4) void convA(const float* __restrict__ audio,
                                                const float* __restrict__ gt,
                                                float* __restrict__ Sg) {
    __shared__ __align__(16) float abI[1280];         //  5,120 B  [P][640] interleaved
    __shared__ __align__(16) float ybuf[4][4][272];   // 17,408 B [wave][ch][2blk*136]

    const int b = blockIdx.x, g = blockIdx.y;
    const int tid = threadIdx.x, w = tid >> 6, lane = tid & 63;
    const float* arow = audio + (size_t)b * N_;

    const int origin = (g << 10) - 32;
    // Interleaved staging: logical j = 2*i + h  <->  sample origin + P*512 + h*256 + i
    for (int idx = tid; idx < 1280; idx += 256) {
        int P = idx / 640, j = idx - P * 640;
        int ii = j >> 1, h = j & 1;
        int gi = origin + (P << 9) + (h << 8) + ii;
        float v = (gi >= 0 && gi < N_) ? arow[gi] : 0.0f;
        abI[P * 640 + (j ^ (((j >> 5) & 1) << 2))] = v;
    }
    __syncthreads();

    for (int G = 0; G < 2; ++G) {
        // wave-uniform tap row base -> scalar loads
        const int rowbase = __builtin_amdgcn_readfirstlane(((w << 3) + (G << 2)) << 6);
        const float* kg = gt + rowbase;

        v2f Y[2][4][4];   // [P][ch][d]; lo = pp=2P, hi = pp=2P+1
#pragma unroll
        for (int P = 0; P < 2; ++P)
#pragma unroll
            for (int ch = 0; ch < 4; ++ch)
#pragma unroll
                for (int d = 0; d < 4; ++d) { Y[P][ch][d].x = 0.0f; Y[P][ch][d].y = 0.0f; }

        f2x2 Ta[4], Tb[4];

        // mid-loop body: taps TM = T(q-1), TC = T(q)
        auto BODY = [&](int q, const f2x2* TM, const f2x2* TC) {
            const int u = lane + q;
            const int p1 = (u << 3) ^ (((u >> 2) & 1) << 2);
#pragma unroll
            for (int P = 0; P < 2; ++P) {
                const float* abP = abI + P * 640;
                const f2x2 A0 = *(const f2x2*)(abP + p1);
                const f2x2 A1 = *(const f2x2*)(abP + (p1 ^ 4));
#pragma unroll
                for (int e = 0; e < 4; ++e) {
                    const v2f a = (e == 0) ? A0.lo : (e == 1) ? A0.hi
                                : (e == 2) ? A1.lo : A1.hi;
#pragma unroll
                    for (int ch = 0; ch < 4; ++ch)
#pragma unroll
                        for (int d = 0; d < 4; ++d) {
                            const int ts = e - 1 - d;          // compile-time
                            if (ts >= 0) PKFMA(Y[P][ch][d], a, TC[ch], ts);
                            else         PKFMA(Y[P][ch][d], a, TM[ch], 4 + ts);
                        }
                }
            }
        };

        // ---- q = 0 peel: k = e-1-d, only k>=0 terms (taps T(0) -> Ta)
        {
#pragma unroll
            for (int ch = 0; ch < 4; ++ch)
                Ta[ch] = *(const f2x2*)(kg + (ch << 6));
            const int u = lane;
            const int p1 = (u << 3) ^ (((u >> 2) & 1) << 2);
#pragma unroll
            for (int P = 0; P < 2; ++P) {
                const float* abP = abI + P * 640;
                const f2x2 A0 = *(const f2x2*)(abP + p1);
                const f2x2 A1 = *(const f2x2*)(abP + (p1 ^ 4));
#pragma unroll
                for (int e = 0; e < 4; ++e) {
                    const v2f a = (e == 0) ? A0.lo : (e == 1) ? A0.hi
                                : (e == 2) ? A1.lo : A1.hi;
#pragma unroll
                    for (int ch = 0; ch < 4; ++ch)
#pragma unroll
                        for (int d = 0; d < 4; ++d) {
                            const int kb = e - 1 - d;          // compile-time
                            if (kb >= 0) PKFMA(Y[P][ch][d], a, Ta[ch], kb);
                        }
                }
            }
        }

        // ---- q = 1..14 in pairs: rotate Ta/Tb (each tap quad loaded once)
#pragma unroll 1
        for (int qq = 1; qq < 15; qq += 2) {
#pragma unroll
            for (int ch = 0; ch < 4; ++ch)
                Tb[ch] = *(const f2x2*)(kg + (ch << 6) + (qq << 2));
            BODY(qq, Ta, Tb);
#pragma unroll
            for (int ch = 0; ch < 4; ++ch)
                Ta[ch] = *(const f2x2*)(kg + (ch << 6) + ((qq + 1) << 2));
            BODY(qq + 1, Tb, Ta);
        }

        // ---- q = 15 (Tm = Ta = T(14))
        {
#pragma unroll
            for (int ch = 0; ch < 4; ++ch)
                Tb[ch] = *(const f2x2*)(kg + (ch << 6) + 60);
            BODY(15, Ta, Tb);
        }

        // ---- q = 16 peel: only ts<0 terms (taps 60..63 = Tb)
        {
            const int u = lane + 16;
            const int p1 = (u << 3) ^ (((u >> 2) & 1) << 2);
#pragma unroll
            for (int P = 0; P < 2; ++P) {
                const float* abP = abI + P * 640;
                const f2x2 A0 = *(const f2x2*)(abP + p1);
                const f2x2 A1 = *(const f2x2*)(abP + (p1 ^ 4));
#pragma unroll
                for (int e = 0; e < 4; ++e) {
                    const v2f a = (e == 0) ? A0.lo : (e == 1) ? A0.hi
                                : (e == 2) ? A1.lo : A1.hi;
#pragma unroll
                    for (int ch = 0; ch < 4; ++ch)
#pragma unroll
                        for (int d = 0; d < 4; ++d) {
                            const int ts = e - 1 - d;          // compile-time
                            if (ts < 0) PKFMA(Y[P][ch][d], a, Tb[ch], 4 + ts);
                        }
                }
            }
        }

        // ---- epilogue per pp (identical math/order)
#pragma unroll
        for (int pp = 0; pp < 4; ++pp) {
            const int P = pp >> 1, h = pp & 1;
#pragma unroll
            for (int ch = 0; ch < 4; ++ch) {
                float4 z;
                z.x = fmaxf(h ? Y[P][ch][0].y : Y[P][ch][0].x, 0.0f);
                z.y = fmaxf(h ? Y[P][ch][1].y : Y[P][ch][1].x, 0.0f);
                z.z = fmaxf(h ? Y[P][ch][2].y : Y[P][ch][2].x, 0.0f);
                z.w = fmaxf(h ? Y[P][ch][3].y : Y[P][ch][3].x, 0.0f);
                *(float4*)(&ybuf[w][ch][((lane >> 5) * 136) + ((lane & 31) << 2)]) = z;
            }
            // numpy pairwise-128: 64 lanes = 4ch x 2blk x 8slots.
            {
                const int ch2 = lane >> 4, blk = (lane >> 3) & 1, j = lane & 7;
                const float* yb = &ybuf[w][ch2][blk * 136 + j];
                float r = yb[0];
#pragma unroll
                for (int m = 1; m < 16; ++m) r = fadd(r, yb[m << 3]);
                float v = fadd(r, __shfl_xor(r, 1));
                v = fadd(v, __shfl_xor(v, 2));
                v = fadd(v, __shfl_xor(v, 4));
                const int jg = (g << 3) + (pp << 1) + blk;
                const int c = (w << 3) + (G << 2) + ch2;
                if (j == 0 && jg < NJ) Sg[((size_t)b * C_ + c) * NJ + jg] = v;
            }
        }
    }
}

// ---------------------------------------------------------------------------
// Kernel B: SNN. ROUND-20: software-pipelined phase chain. The serial
// phase sequence (bushyMem -> icCur -> icMem -> acCur -> acMem) previously
// ran as whole-T barrier phases, the membrane ones on 50/50/10 threads with
// 15 waves idle: latency chain ~= sum(phases). Now T=124 is split into 4
// chunks of 31 and step s runs concurrently on DISJOINT thread ranges:
//   bushyMem(chunk s) [tid 914-963] || icCur(s-1) [0-759] ||
//   icMem(s-2) [964-1013]           || acCur(s-3) [760-913] ||
//   acMem(s-4)+stores [1014-1023]
// 8 steps; per-step buffers disjoint (membrane writes chunk s, readers use
// older chunks); membrane state in registers of fixed threads; per-output
// arithmetic order unchanged: bit-exact.
// ---------------------------------------------------------------------------
__global__ __launch_bounds__(TB_, 1) void snnB(const float* __restrict__ Sg,
                                               const float* __restrict__ Wb,
                                               const float* __restrict__ Wic,
                                               const float* __restrict__ Wac,
                                               float* __restrict__ out) {
    __shared__ float sWb[HID_ * 321];                 // 64,200 B (321%32==1)
    __shared__ __align__(16) float sWic[HID_ * 52];   // 10,400 B
    __shared__ __align__(16) float sWac[OUT_ * 52];   //  2,080 B
    __shared__ u32   mask[128 * 10];                  //  5,120 B (rows 124..127 zero)
    __shared__ __align__(16) float cur[T_ * CURS];    // 25,792 B
    __shared__ __align__(16) float icur[T_ * CURS];   // 25,792 B
    __shared__ float acur[T_ * 12];                   //  5,952 B   (total ~139.3 KB)

    const int b = blockIdx.x, tid = threadIdx.x;

    for (int i = tid; i < HID_ * 320; i += TB_) {
        int r = i / 320;
        sWb[r * 321 + (i - r * 320)] = Wb[i];
    }
    for (int i = tid; i < HID_ * HID_; i += TB_) {
        int r = i / 50;
        sWic[r * 52 + (i - r * 50)] = Wic[i];
    }
    for (int i = tid; i < OUT_ * HID_; i += TB_) {
        int r = i / 50;
        sWac[r * 52 + (i - r * 50)] = Wac[i];
    }

    // ---- AN spike bitmasks: word (t, wd) covers i in [32wd, 32wd+32)
    const float* Sb = Sg + (size_t)b * C_ * NJ;
    for (int idx = tid; idx < 1280; idx += TB_) {
        if (idx >= T_ * 10) { mask[idx] = 0; continue; }
        int t = idx / 10, wd = idx - t * 10;
        u32 m = 0;
        int c_prev = -1;
        float env = 0.0f;
        for (int k = 0; k < 32; ++k) {
            int i = wd * 32 + k;
            int c = i / 10, s = i - c * 10;
            if (c != c_prev) {
                env = fmul(fadd(Sb[c * NJ + t], Sb[c * NJ + t + 1]), 0.00390625f);
                c_prev = c;
            }
            float sf = (s == 9) ? 1.5f : (float)(0.5 + (double)s * (1.0 / 9.0));
            if (fsub(fmul(env, sf), 0.5f) > 0.0f) m |= (1u << k);
        }
        mask[idx] = m;
    }
    __syncthreads();

    // ---- Bushy currents: 8 t-chains per weight-row pass (t = t0 + 16m),
    //      packed as 4 v2f accumulators (v_pk_add_f32)
    if (tid < 16 * HID_) {
        const int t0 = tid / 50, h = tid - t0 * 50;
        const float* wr = sWb + h * 321;
        const u32* mrow = mask + t0 * 10;
        v2f A0v = {0.0f, 0.0f}, A1v = {0.0f, 0.0f};
        v2f A2v = {0.0f, 0.0f}, A3v = {0.0f, 0.0f};
#pragma unroll 1
        for (int wi = 0; wi < 10; ++wi) {
            const u32 w0 = mrow[wi], w1 = mrow[160 + wi];
            const u32 w2 = mrow[320 + wi], w3 = mrow[480 + wi];
            const u32 w4 = mrow[640 + wi], w5 = mrow[800 + wi];
            const u32 w6 = mrow[960 + wi], w7 = mrow[1120 + wi];
#pragma unroll
            for (int b2 = 0; b2 < 32; ++b2) {
                const float wv = wr[(wi << 5) + b2];
                const int iw = __float_as_int(wv);
                v2f p0, p1, p2, p3;
                p0.x = __int_as_float(iw & __builtin_amdgcn_sbfe((int)w0, b2, 1));
                p0.y = __int_as_float(iw & __builtin_amdgcn_sbfe((int)w1, b2, 1));
                p1.x = __int_as_float(iw & __builtin_amdgcn_sbfe((int)w2, b2, 1));
                p1.y = __int_as_float(iw & __builtin_amdgcn_sbfe((int)w3, b2, 1));
                p2.x = __int_as_float(iw & __builtin_amdgcn_sbfe((int)w4, b2, 1));
                p2.y = __int_as_float(iw & __builtin_amdgcn_sbfe((int)w5, b2, 1));
                p3.x = __int_as_float(iw & __builtin_amdgcn_sbfe((int)w6, b2, 1));
                p3.y = __int_as_float(iw & __builtin_amdgcn_sbfe((int)w7, b2, 1));
                A0v = A0v + p0;   // v_pk_add_f32: each half IEEE fadd
                A1v = A1v + p1;
                A2v = A2v + p2;
                A3v = A3v + p3;
            }
        }
        cur[(t0      ) * CURS + h] = A0v.x;
        cur[(t0 + 16 ) * CURS + h] = A0v.y;
        cur[(t0 + 32 ) * CURS + h] = A1v.x;
        cur[(t0 + 48 ) * CURS + h] = A1v.y;
        cur[(t0 + 64 ) * CURS + h] = A2v.x;
        cur[(t0 + 80 ) * CURS + h] = A2v.y;
        cur[(t0 + 96 ) * CURS + h] = A3v.x;
        if (t0 + 112 < T_) cur[(t0 + 112) * CURS + h] = A3v.y;
    }
    __syncthreads();

    // ---- Pipelined phase chain over 4 chunks of 31 t-steps, 8 steps.
    float memB = 0.0f, memI = 0.0f, memA = 0.0f;
#pragma unroll 1
    for (int s = 0; s < 8; ++s) {
        // role 1: bushy membrane, chunk s  [tid 914..963]
        if (s < 4 && tid >= 914 && tid < 964) {
            const int h = tid - 914, tb = s * 31;
            float cc[31];
#pragma unroll
            for (int k = 0; k < 31; ++k) cc[k] = cur[(tb + k) * CURS + h];
#pragma unroll
            for (int k = 0; k < 31; ++k) {
                float m = fadd(fmul(0.95f, memB), cc[k]);
                float sp = (fsub(m, 1.0f) > 0.0f) ? 1.0f : 0.0f;
                memB = fsub(m, sp);
                cur[(tb + k) * CURS + h] = sp;
            }
        }
        // role 2: IC currents, chunk s-1  [tid 0..759], 775 items
        if (s >= 1 && s <= 4 && tid < 760) {
            const int tb = (s - 1) * 31;
            for (int idx = tid; idx < 775; idx += 760) {
                int tl = idx / 25, hp = idx - tl * 25;
                int t = tb + tl;
                const float* w0 = sWic + hp * 52;
                const float* w1 = sWic + (hp + 25) * 52;
                const float* sb = cur + t * CURS;
                float acc0 = 0.0f, acc1 = 0.0f;
#pragma unroll
                for (int g4 = 0; g4 < 12; ++g4) {
                    const float4 s4 = *(const float4*)(sb + (g4 << 2));
                    const float4 wa = *(const float4*)(w0 + (g4 << 2));
                    const float4 wb = *(const float4*)(w1 + (g4 << 2));
                    acc0 = fmaf(s4.x, wa.x, acc0);  acc1 = fmaf(s4.x, wb.x, acc1);
                    acc0 = fmaf(s4.y, wa.y, acc0);  acc1 = fmaf(s4.y, wb.y, acc1);
                    acc0 = fmaf(s4.z, wa.z, acc0);  acc1 = fmaf(s4.z, wb.z, acc1);
                    acc0 = fmaf(s4.w, wa.w, acc0);  acc1 = fmaf(s4.w, wb.w, acc1);
                }
                acc0 = fmaf(sb[48], w0[48], acc0);  acc1 = fmaf(sb[48], w1[48], acc1);
                acc0 = fmaf(sb[49], w0[49], acc0);  acc1 = fmaf(sb[49], w1[49], acc1);
                icur[t * CURS + hp] = acc0;
                icur[t * CURS + hp + 25] = acc1;
            }
        }
        // role 3: IC membrane, chunk s-2  [tid 964..1013]
        if (s >= 2 && s <= 5 && tid >= 964 && tid < 1014) {
            const int h = tid - 964, tb = (s - 2) * 31;
            float cc[31];
#pragma unroll
            for (int k = 0; k < 31; ++k) cc[k] = icur[(tb + k) * CURS + h];
#pragma unroll
            for (int k = 0; k < 31; ++k) {
                float m = fadd(fmul(0.95f, memI), cc[k]);
                float sp = (fsub(m, 1.0f) > 0.0f) ? 1.0f : 0.0f;
                memI = fsub(m, sp);
                icur[(tb + k) * CURS + h] = sp;
            }
        }
        // role 4: AC currents, chunk s-3  [tid 760..913], 155 items
        if (s >= 3 && s <= 6 && tid >= 760 && tid < 914) {
            const int tb = (s - 3) * 31;
            for (int idx = tid - 760; idx < 155; idx += 154) {
                int tl = idx / 5, op = idx - tl * 5;
                int t = tb + tl;
                const float* w0 = sWac + op * 52;
                const float* w1 = sWac + (op + 5) * 52;
                const float* sb = icur + t * CURS;
                float acc0 = 0.0f, acc1 = 0.0f;
#pragma unroll
                for (int g4 = 0; g4 < 12; ++g4) {
                    const float4 s4 = *(const float4*)(sb + (g4 << 2));
                    const float4 wa = *(const float4*)(w0 + (g4 << 2));
                    const float4 wb = *(const float4*)(w1 + (g4 << 2));
                    acc0 = fmaf(s4.x, wa.x, acc0);  acc1 = fmaf(s4.x, wb.x, acc1);
                    acc0 = fmaf(s4.y, wa.y, acc0);  acc1 = fmaf(s4.y, wb.y, acc1);
                    acc0 = fmaf(s4.z, wa.z, acc0);  acc1 = fmaf(s4.z, wb.z, acc1);
                    acc0 = fmaf(s4.w, wa.w, acc0);  acc1 = fmaf(s4.w, wb.w, acc1);
                }
                acc0 = fmaf(sb[48], w0[48], acc0);  acc1 = fmaf(sb[48], w1[48], acc1);
                acc0 = fmaf(sb[49], w0[49], acc0);  acc1 = fmaf(sb[49], w1[49], acc1);
                acur[t * 12 + op] = acc0;
                acur[t * 12 + op + 5] = acc1;
            }
        }
        // role 5: AC membrane + stores, chunk s-4  [tid 1014..1023]
        if (s >= 4 && tid >= 1014) {
            const int o = tid - 1014, tb = (s - 4) * 31;
            float cc[31];
#pragma unroll
            for (int k = 0; k < 31; ++k) cc[k] = acur[(tb + k) * 12 + o];
#pragma unroll
            for (int k = 0; k < 31; ++k) {
                float m = fadd(fmul(0.95f, memA), cc[k]);
                float sp = (fsub(m, 1.0f) > 0.0f) ? 1.0f : 0.0f;
                float mo = fsub(m, sp);
                memA = mo;
                size_t base = ((size_t)b * T_ + (tb + k)) * OUT_ + o;
                out[base] = sp;
                out[(size_t)(B_ * T_ * OUT_) + base] = mo;
            }
        }
        __syncthreads();
    }
}

// ---------------------------------------------------------------------------
extern "C" void kernel_launch(void* const* d_in, const int* in_sizes, int n_in,
                              void* d_out, int out_size, void* d_ws, size_t ws_size,
                              hipStream_t stream) {
    (void)in_sizes; (void)n_in; (void)out_size; (void)ws_size;
    const float* audio = (const float*)d_in[0];
    const float* gt    = (const float*)d_in[1];
    const float* Wb    = (const float*)d_in[2];
    const float* Wic   = (const float*)d_in[3];
    const float* Wac   = (const float*)d_in[4];

    float* Sg = (float*)d_ws;   // needs 256*32*125*4 = 4,096,000 B of ws

    convA<<<dim3(B_, 16), dim3(256), 0, stream>>>(audio, gt, Sg);
    snnB<<<dim3(B_), dim3(TB_), 0, stream>>>(Sg, Wb, Wic, Wac, (float*)d_out);
}

// Round 7
// 285.943 us; speedup vs baseline: 1.1049x; 1.1049x over previous
//
#include <hip/hip_runtime.h>

// Problem dims
#define B_   256
#define N_   16000
#define C_   32
#define K_   64
#define T_   124
#define NJ   125      // 128-sample half-window block sums, j = 0..124
#define HID_ 50
#define OUT_ 10
#define TB_  1024     // snnB block size
#define CURS 52       // padded stride for cur/icur (float4-aligned)
#define WBS  324      // sWb row stride (float4-aligned; bank-spread via +4)

typedef unsigned int u32;
typedef float v2f __attribute__((ext_vector_type(2)));
struct __align__(16) f2x2 { v2f lo, hi; };

// Exact single f32 ops (prevent fma contraction / reassociation).
__device__ __forceinline__ float fadd(float a, float b) { return __fadd_rn(a, b); }
__device__ __forceinline__ float fmul(float a, float b) { return __fmul_rn(a, b); }
__device__ __forceinline__ float fsub(float a, float b) { return __fsub_rn(a, b); }

// Packed f32 FMA: y.lo += a.lo*tap, y.hi += a.hi*tap, tap = slot k of pair-pair T,
// broadcast via VOP3P op_sel. T lives in SGPRs (s_load'd, wave-uniform): VOP3P
// permits one SGPR source. Each half is an IEEE f32 FMA == fmaf: bit-identical.
__device__ __forceinline__ void PKFMA(v2f& y, v2f a, const f2x2& T, int k) {
    switch (k) {
    case 0:  asm("v_pk_fma_f32 %0, %1, %2, %0 op_sel:[0,0,0] op_sel_hi:[1,0,1]"
                 : "+v"(y) : "v"(a), "s"(T.lo)); break;
    case 1:  asm("v_pk_fma_f32 %0, %1, %2, %0 op_sel:[0,1,0] op_sel_hi:[1,1,1]"
                 : "+v"(y) : "v"(a), "s"(T.lo)); break;
    case 2:  asm("v_pk_fma_f32 %0, %1, %2, %0 op_sel:[0,0,0] op_sel_hi:[1,0,1]"
                 : "+v"(y) : "v"(a), "s"(T.hi)); break;
    default: asm("v_pk_fma_f32 %0, %1, %2, %0 op_sel:[0,1,0] op_sel_hi:[1,1,1]"
                 : "+v"(y) : "v"(a), "s"(T.hi)); break;
    }
}

// ---------------------------------------------------------------------------
// Kernel A: conv (SAME pad_lo=31, correlation, sequential-k f32 FMA) + relu +
// numpy-pairwise 128-block sums -> Sg[b][c][j].
//
// ROUND-21: exact revert to the r4/r18 structure (measured 177-182 us, VGPR
// 52, no spills) — best of all measured variants. r19 (4-pass, higher occ)
// and r20 (tap rotation, VGPR 64) both regressed: kernel is FMA-pipe-bound
// (floor ~109 us @2.4GHz; ~150-160 at sustained clock), so extra passes or
// extra live registers cost, occupancy does not pay.
// ---------------------------------------------------------------------------
__global__ __launch_bounds__(256, 4) void convA(const float* __restrict__ audio,
                                                const float* __restrict__ gt,
                                                float* __restrict__ Sg) {
    __shared__ __align__(16) float abI[1280];         //  5,120 B  [P][640] interleaved
    __shared__ __align__(16) float ybuf[4][4][272];   // 17,408 B [wave][ch][2blk*136]

    const int b = blockIdx.x, g = blockIdx.y;
    const int tid = threadIdx.x, w = tid >> 6, lane = tid & 63;
    const float* arow = audio + (size_t)b * N_;

    const int origin = (g << 10) - 32;
    // Interleaved staging: logical j = 2*i + h  <->  sample origin + P*512 + h*256 + i
    for (int idx = tid; idx < 1280; idx += 256) {
        int P = idx / 640, j = idx - P * 640;
        int ii = j >> 1, h = j & 1;
        int gi = origin + (P << 9) + (h << 8) + ii;
        float v = (gi >= 0 && gi < N_) ? arow[gi] : 0.0f;
        abI[P * 640 + (j ^ (((j >> 5) & 1) << 2))] = v;
    }
    __syncthreads();

    for (int G = 0; G < 2; ++G) {
        // wave-uniform tap row base -> scalar loads
        const int rowbase = __builtin_amdgcn_readfirstlane(((w << 3) + (G << 2)) << 6);
        const float* kg = gt + rowbase;

        v2f Y[2][4][4];   // [P][ch][d]; lo = pp=2P, hi = pp=2P+1
#pragma unroll
        for (int P = 0; P < 2; ++P)
#pragma unroll
            for (int ch = 0; ch < 4; ++ch)
#pragma unroll
                for (int d = 0; d < 4; ++d) { Y[P][ch][d].x = 0.0f; Y[P][ch][d].y = 0.0f; }

        // ---- q = 0 peel: k = e-1-d, only k>=0 terms (all from Tc)
        {
            f2x2 Tc[4];
#pragma unroll
            for (int ch = 0; ch < 4; ++ch)
                Tc[ch] = *(const f2x2*)(kg + (ch << 6));
            const int u = lane;
            const int p1 = (u << 3) ^ (((u >> 2) & 1) << 2);
#pragma unroll
            for (int P = 0; P < 2; ++P) {
                const float* abP = abI + P * 640;
                const f2x2 A0 = *(const f2x2*)(abP + p1);
                const f2x2 A1 = *(const f2x2*)(abP + (p1 ^ 4));
#pragma unroll
                for (int e = 0; e < 4; ++e) {
                    const v2f a = (e == 0) ? A0.lo : (e == 1) ? A0.hi
                                : (e == 2) ? A1.lo : A1.hi;
#pragma unroll
                    for (int ch = 0; ch < 4; ++ch)
#pragma unroll
                        for (int d = 0; d < 4; ++d) {
                            const int kb = e - 1 - d;          // compile-time
                            if (kb >= 0) PKFMA(Y[P][ch][d], a, Tc[ch], kb);
                        }
                }
            }
        }

        // ---- q = 1..15: boundary-free, NOT unrolled (live set = 1 iter)
#pragma unroll 1
        for (int q = 1; q < 16; ++q) {
            f2x2 Tm[4], Tc[4];   // taps 4(q-1)+{0..3} and 4q+{0..3} (SGPR)
#pragma unroll
            for (int ch = 0; ch < 4; ++ch) {
                Tm[ch] = *(const f2x2*)(kg + (ch << 6) + ((q - 1) << 2));
                Tc[ch] = *(const f2x2*)(kg + (ch << 6) + (q << 2));
            }
            const int u = lane + q;
            const int p1 = (u << 3) ^ (((u >> 2) & 1) << 2);
#pragma unroll
            for (int P = 0; P < 2; ++P) {
                const float* abP = abI + P * 640;
                const f2x2 A0 = *(const f2x2*)(abP + p1);
                const f2x2 A1 = *(const f2x2*)(abP + (p1 ^ 4));
#pragma unroll
                for (int e = 0; e < 4; ++e) {
                    const v2f a = (e == 0) ? A0.lo : (e == 1) ? A0.hi
                                : (e == 2) ? A1.lo : A1.hi;
#pragma unroll
                    for (int ch = 0; ch < 4; ++ch)
#pragma unroll
                        for (int d = 0; d < 4; ++d) {
                            const int ts = e - 1 - d;          // compile-time
                            if (ts >= 0) PKFMA(Y[P][ch][d], a, Tc[ch], ts);
                            else         PKFMA(Y[P][ch][d], a, Tm[ch], 4 + ts);
                        }
                }
            }
        }

        // ---- q = 16 peel: only ts<0 terms (taps 60..63)
        {
            f2x2 Tm[4];
#pragma unroll
            for (int ch = 0; ch < 4; ++ch)
                Tm[ch] = *(const f2x2*)(kg + (ch << 6) + 60);
            const int u = lane + 16;
            const int p1 = (u << 3) ^ (((u >> 2) & 1) << 2);
#pragma unroll
            for (int P = 0; P < 2; ++P) {
                const float* abP = abI + P * 640;
                const f2x2 A0 = *(const f2x2*)(abP + p1);
                const f2x2 A1 = *(const f2x2*)(abP + (p1 ^ 4));
#pragma unroll
                for (int e = 0; e < 4; ++e) {
                    const v2f a = (e == 0) ? A0.lo : (e == 1) ? A0.hi
                                : (e == 2) ? A1.lo : A1.hi;
#pragma unroll
                    for (int ch = 0; ch < 4; ++ch)
#pragma unroll
                        for (int d = 0; d < 4; ++d) {
                            const int ts = e - 1 - d;          // compile-time
                            if (ts < 0) PKFMA(Y[P][ch][d], a, Tm[ch], 4 + ts);
                        }
                }
            }
        }

        // ---- epilogue per pp (identical math/order)
#pragma unroll
        for (int pp = 0; pp < 4; ++pp) {
            const int P = pp >> 1, h = pp & 1;
#pragma unroll
            for (int ch = 0; ch < 4; ++ch) {
                float4 z;
                z.x = fmaxf(h ? Y[P][ch][0].y : Y[P][ch][0].x, 0.0f);
                z.y = fmaxf(h ? Y[P][ch][1].y : Y[P][ch][1].x, 0.0f);
                z.z = fmaxf(h ? Y[P][ch][2].y : Y[P][ch][2].x, 0.0f);
                z.w = fmaxf(h ? Y[P][ch][3].y : Y[P][ch][3].x, 0.0f);
                *(float4*)(&ybuf[w][ch][((lane >> 5) * 136) + ((lane & 31) << 2)]) = z;
            }
            // numpy pairwise-128: 64 lanes = 4ch x 2blk x 8slots.
            {
                const int ch2 = lane >> 4, blk = (lane >> 3) & 1, j = lane & 7;
                const float* yb = &ybuf[w][ch2][blk * 136 + j];
                float r = yb[0];
#pragma unroll
                for (int m = 1; m < 16; ++m) r = fadd(r, yb[m << 3]);
                float v = fadd(r, __shfl_xor(r, 1));
                v = fadd(v, __shfl_xor(v, 2));
                v = fadd(v, __shfl_xor(v, 4));
                const int jg = (g << 3) + (pp << 1) + blk;
                const int c = (w << 3) + (G << 2) + ch2;
                if (j == 0 && jg < NJ) Sg[((size_t)b * C_ + c) * NJ + jg] = v;
            }
        }
    }
}

// ---------------------------------------------------------------------------
// Kernel B: SNN. ROUND-21: r5 flat phase structure (proven 118us; r6's
// pipeline regressed) with work cuts:
//  - bushy currents: t-quad x h-pair threads (775): sbfe shared across the
//    h-pair -> 16 VALU + 2 ds_read per 8 outputs (was 20 + 1 per 8).
//  - IC currents: t-quad x h-pair, g4-outer: weight float4 read once per 8
//    outputs (was once per 2): IC LDS traffic halved. AC likewise.
//  - sWb staged with float4 (stride 324, rows 16B-aligned): 4 rounds vs 16.
// Per-output accumulation orders (i asc / g asc) unchanged: bit-exact.
// ---------------------------------------------------------------------------
__global__ __launch_bounds__(TB_, 1) void snnB(const float* __restrict__ Sg,
                                               const float* __restrict__ Wb,
                                               const float* __restrict__ Wic,
                                               const float* __restrict__ Wac,
                                               float* __restrict__ out) {
    __shared__ __align__(16) float sWb[HID_ * WBS];   // 64,800 B
    __shared__ __align__(16) float sWic[HID_ * 52];   // 10,400 B
    __shared__ __align__(16) float sWac[OUT_ * 52];   //  2,080 B
    __shared__ u32   mask[128 * 10];                  //  5,120 B (rows 124..127 zero)
    __shared__ __align__(16) float cur[T_ * CURS];    // 25,792 B
    __shared__ __align__(16) float icur[T_ * CURS];   // 25,792 B
    __shared__ float acur[T_ * 12];                   //  5,952 B  (total ~139.9 KB)

    const int b = blockIdx.x, tid = threadIdx.x;

    // sWb: float4 staging (320 % 4 == 0 -> each float4 within one row)
    for (int i4 = tid; i4 < 4000; i4 += TB_) {
        const int i = i4 << 2;
        const int r = i / 320, col = i - r * 320;
        *(float4*)(&sWb[r * WBS + col]) = *(const float4*)(Wb + i);
    }
    for (int i = tid; i < HID_ * HID_; i += TB_) {
        int r = i / 50;
        sWic[r * 52 + (i - r * 50)] = Wic[i];
    }
    for (int i = tid; i < OUT_ * HID_; i += TB_) {
        int r = i / 50;
        sWac[r * 52 + (i - r * 50)] = Wac[i];
    }

    // ---- AN spike bitmasks: word (t, wd) covers i in [32wd, 32wd+32)
    const float* Sb = Sg + (size_t)b * C_ * NJ;
    for (int idx = tid; idx < 1280; idx += TB_) {
        if (idx >= T_ * 10) { mask[idx] = 0; continue; }
        int t = idx / 10, wd = idx - t * 10;
        u32 m = 0;
        int c_prev = -1;
        float env = 0.0f;
        for (int k = 0; k < 32; ++k) {
            int i = wd * 32 + k;
            int c = i / 10, s = i - c * 10;
            if (c != c_prev) {
                env = fmul(fadd(Sb[c * NJ + t], Sb[c * NJ + t + 1]), 0.00390625f);
                c_prev = c;
            }
            float sf = (s == 9) ? 1.5f : (float)(0.5 + (double)s * (1.0 / 9.0));
            if (fsub(fmul(env, sf), 0.5f) > 0.0f) m |= (1u << k);
        }
        mask[idx] = m;
    }
    __syncthreads();

    // ---- Bushy currents: t-quad (t0+{0,31,62,93}) x h-pair (hp, hp+25)
    if (tid < 31 * 25) {
        const int t0 = tid / 25, hp = tid - t0 * 25;
        const float* wr0 = sWb + hp * WBS;
        const float* wr1 = sWb + (hp + 25) * WBS;
        const u32* mrow = mask + t0 * 10;
        v2f a0 = {0.0f, 0.0f}, a1 = {0.0f, 0.0f};   // x = h=hp, y = h=hp+25
        v2f a2 = {0.0f, 0.0f}, a3 = {0.0f, 0.0f};
#pragma unroll 1
        for (int wi = 0; wi < 10; ++wi) {
            const u32 w0 = mrow[wi],       w1 = mrow[310 + wi];
            const u32 w2 = mrow[620 + wi], w3 = mrow[930 + wi];
#pragma unroll
            for (int b2 = 0; b2 < 32; ++b2) {
                const int i = (wi << 5) + b2;
                const int iw0 = __float_as_int(wr0[i]);
                const int iw1 = __float_as_int(wr1[i]);
                const int s0 = __builtin_amdgcn_sbfe((int)w0, b2, 1);
                const int s1 = __builtin_amdgcn_sbfe((int)w1, b2, 1);
                const int s2 = __builtin_amdgcn_sbfe((int)w2, b2, 1);
                const int s3 = __builtin_amdgcn_sbfe((int)w3, b2, 1);
                v2f p0, p1, p2, p3;
                p0.x = __int_as_float(iw0 & s0);  p0.y = __int_as_float(iw1 & s0);
                p1.x = __int_as_float(iw0 & s1);  p1.y = __int_as_float(iw1 & s1);
                p2.x = __int_as_float(iw0 & s2);  p2.y = __int_as_float(iw1 & s2);
                p3.x = __int_as_float(iw0 & s3);  p3.y = __int_as_float(iw1 & s3);
                a0 = a0 + p0;   // v_pk_add_f32: each half IEEE fadd (+0.0 on clear)
                a1 = a1 + p1;
                a2 = a2 + p2;
                a3 = a3 + p3;
            }
        }
        cur[(t0     ) * CURS + hp] = a0.x;  cur[(t0     ) * CURS + hp + 25] = a0.y;
        cur[(t0 + 31) * CURS + hp] = a1.x;  cur[(t0 + 31) * CURS + hp + 25] = a1.y;
        cur[(t0 + 62) * CURS + hp] = a2.x;  cur[(t0 + 62) * CURS + hp + 25] = a2.y;
        cur[(t0 + 93) * CURS + hp] = a3.x;  cur[(t0 + 93) * CURS + hp + 25] = a3.y;
    }
    __syncthreads();

    // ---- Bushy membrane chains: batch-8 prefetch, serial chain in regs
    if (tid < HID_) {
        float mem = 0.0f;
        for (int t0 = 0; t0 < 120; t0 += 8) {
            float c0[8];
#pragma unroll
            for (int k = 0; k < 8; ++k) c0[k] = cur[(t0 + k) * CURS + tid];
#pragma unroll
            for (int k = 0; k < 8; ++k) {
                float m = fadd(fmul(0.95f, mem), c0[k]);
                float sp = (fsub(m, 1.0f) > 0.0f) ? 1.0f : 0.0f;
                mem = fsub(m, sp);
                cur[(t0 + k) * CURS + tid] = sp;
            }
        }
        for (int t = 120; t < T_; ++t) {
            float m = fadd(fmul(0.95f, mem), cur[t * CURS + tid]);
            float sp = (fsub(m, 1.0f) > 0.0f) ? 1.0f : 0.0f;
            mem = fsub(m, sp);
            cur[t * CURS + tid] = sp;
        }
    }
    __syncthreads();

    // ---- IC currents: t-quad x h-pair, g4-outer (weights read once/8 out)
    if (tid < 31 * 25) {
        const int t0 = tid / 25, hp = tid - t0 * 25;
        const float* w0 = sWic + hp * 52;
        const float* w1 = sWic + (hp + 25) * 52;
        const float* sb0 = cur + (t0     ) * CURS;
        const float* sb1 = cur + (t0 + 31) * CURS;
        const float* sb2 = cur + (t0 + 62) * CURS;
        const float* sb3 = cur + (t0 + 93) * CURS;
        float A00 = 0.0f, A01 = 0.0f, A10 = 0.0f, A11 = 0.0f;
        float A20 = 0.0f, A21 = 0.0f, A30 = 0.0f, A31 = 0.0f;
#pragma unroll
        for (int g4 = 0; g4 < 12; ++g4) {
            const float4 wa = *(const float4*)(w0 + (g4 << 2));
            const float4 wb = *(const float4*)(w1 + (g4 << 2));
            const float4 s0 = *(const float4*)(sb0 + (g4 << 2));
            const float4 s1 = *(const float4*)(sb1 + (g4 << 2));
            const float4 s2 = *(const float4*)(sb2 + (g4 << 2));
            const float4 s3 = *(const float4*)(sb3 + (g4 << 2));
            A00 = fmaf(s0.x, wa.x, A00); A00 = fmaf(s0.y, wa.y, A00);
            A00 = fmaf(s0.z, wa.z, A00); A00 = fmaf(s0.w, wa.w, A00);
            A01 = fmaf(s0.x, wb.x, A01); A01 = fmaf(s0.y, wb.y, A01);
            A01 = fmaf(s0.z, wb.z, A01); A01 = fmaf(s0.w, wb.w, A01);
            A10 = fmaf(s1.x, wa.x, A10); A10 = fmaf(s1.y, wa.y, A10);
            A10 = fmaf(s1.z, wa.z, A10); A10 = fmaf(s1.w, wa.w, A10);
            A11 = fmaf(s1.x, wb.x, A11); A11 = fmaf(s1.y, wb.y, A11);
            A11 = fmaf(s1.z, wb.z, A11); A11 = fmaf(s1.w, wb.w, A11);
            A20 = fmaf(s2.x, wa.x, A20); A20 = fmaf(s2.y, wa.y, A20);
            A20 = fmaf(s2.z, wa.z, A20); A20 = fmaf(s2.w, wa.w, A20);
            A21 = fmaf(s2.x, wb.x, A21); A21 = fmaf(s2.y, wb.y, A21);
            A21 = fmaf(s2.z, wb.z, A21); A21 = fmaf(s2.w, wb.w, A21);
            A30 = fmaf(s3.x, wa.x, A30); A30 = fmaf(s3.y, wa.y, A30);
            A30 = fmaf(s3.z, wa.z, A30); A30 = fmaf(s3.w, wa.w, A30);
            A31 = fmaf(s3.x, wb.x, A31); A31 = fmaf(s3.y, wb.y, A31);
            A31 = fmaf(s3.z, wb.z, A31); A31 = fmaf(s3.w, wb.w, A31);
        }
        A00 = fmaf(sb0[48], w0[48], A00); A00 = fmaf(sb0[49], w0[49], A00);
        A01 = fmaf(sb0[48], w1[48], A01); A01 = fmaf(sb0[49], w1[49], A01);
        A10 = fmaf(sb1[48], w0[48], A10); A10 = fmaf(sb1[49], w0[49], A10);
        A11 = fmaf(sb1[48], w1[48], A11); A11 = fmaf(sb1[49], w1[49], A11);
        A20 = fmaf(sb2[48], w0[48], A20); A20 = fmaf(sb2[49], w0[49], A20);
        A21 = fmaf(sb2[48], w1[48], A21); A21 = fmaf(sb2[49], w1[49], A21);
        A30 = fmaf(sb3[48], w0[48], A30); A30 = fmaf(sb3[49], w0[49], A30);
        A31 = fmaf(sb3[48], w1[48], A31); A31 = fmaf(sb3[49], w1[49], A31);
        icur[(t0     ) * CURS + hp] = A00;  icur[(t0     ) * CURS + hp + 25] = A01;
        icur[(t0 + 31) * CURS + hp] = A10;  icur[(t0 + 31) * CURS + hp + 25] = A11;
        icur[(t0 + 62) * CURS + hp] = A20;  icur[(t0 + 62) * CURS + hp + 25] = A21;
        icur[(t0 + 93) * CURS + hp] = A30;  icur[(t0 + 93) * CURS + hp + 25] = A31;
    }
    __syncthreads();

    // ---- IC membrane chains: batch-8
    if (tid < HID_) {
        float mem = 0.0f;
        for (int t0 = 0; t0 < 120; t0 += 8) {
            float c0[8];
#pragma unroll
            for (int k = 0; k < 8; ++k) c0[k] = icur[(t0 + k) * CURS + tid];
#pragma unroll
            for (int k = 0; k < 8; ++k) {
                float m = fadd(fmul(0.95f, mem), c0[k]);
                float sp = (fsub(m, 1.0f) > 0.0f) ? 1.0f : 0.0f;
                mem = fsub(m, sp);
                icur[(t0 + k) * CURS + tid] = sp;
            }
        }
        for (int t = 120; t < T_; ++t) {
            float m = fadd(fmul(0.95f, mem), icur[t * CURS + tid]);
            float sp = (fsub(m, 1.0f) > 0.0f) ? 1.0f : 0.0f;
            mem = fsub(m, sp);
            icur[t * CURS + tid] = sp;
        }
    }
    __syncthreads();

    // ---- AC currents: t-quad x o-pair (155 threads), g4-outer
    if (tid < 31 * 5) {
        const int t0 = tid / 5, op = tid - t0 * 5;
        const float* w0 = sWac + op * 52;
        const float* w1 = sWac + (op + 5) * 52;
        const float* sb0 = icur + (t0     ) * CURS;
        const float* sb1 = icur + (t0 + 31) * CURS;
        const float* sb2 = icur + (t0 + 62) * CURS;
        const float* sb3 = icur + (t0 + 93) * CURS;
        float A00 = 0.0f, A01 = 0.0f, A10 = 0.0f, A11 = 0.0f;
        float A20 = 0.0f, A21 = 0.0f, A30 = 0.0f, A31 = 0.0f;
#pragma unroll
        for (int g4 = 0; g4 < 12; ++g4) {
            const float4 wa = *(const float4*)(w0 + (g4 << 2));
            const float4 wb = *(const float4*)(w1 + (g4 << 2));
            const float4 s0 = *(const float4*)(sb0 + (g4 << 2));
            const float4 s1 = *(const float4*)(sb1 + (g4 << 2));
            const float4 s2 = *(const float4*)(sb2 + (g4 << 2));
            const float4 s3 = *(const float4*)(sb3 + (g4 << 2));
            A00 = fmaf(s0.x, wa.x, A00); A00 = fmaf(s0.y, wa.y, A00);
            A00 = fmaf(s0.z, wa.z, A00); A00 = fmaf(s0.w, wa.w, A00);
            A01 = fmaf(s0.x, wb.x, A01); A01 = fmaf(s0.y, wb.y, A01);
            A01 = fmaf(s0.z, wb.z, A01); A01 = fmaf(s0.w, wb.w, A01);
            A10 = fmaf(s1.x, wa.x, A10); A10 = fmaf(s1.y, wa.y, A10);
            A10 = fmaf(s1.z, wa.z, A10); A10 = fmaf(s1.w, wa.w, A10);
            A11 = fmaf(s1.x, wb.x, A11); A11 = fmaf(s1.y, wb.y, A11);
            A11 = fmaf(s1.z, wb.z, A11); A11 = fmaf(s1.w, wb.w, A11);
            A20 = fmaf(s2.x, wa.x, A20); A20 = fmaf(s2.y, wa.y, A20);
            A20 = fmaf(s2.z, wa.z, A20); A20 = fmaf(s2.w, wa.w, A20);
            A21 = fmaf(s2.x, wb.x, A21); A21 = fmaf(s2.y, wb.y, A21);
            A21 = fmaf(s2.z, wb.z, A21); A21 = fmaf(s2.w, wb.w, A21);
            A30 = fmaf(s3.x, wa.x, A30); A30 = fmaf(s3.y, wa.y, A30);
            A30 = fmaf(s3.z, wa.z, A30); A30 = fmaf(s3.w, wa.w, A30);
            A31 = fmaf(s3.x, wb.x, A31); A31 = fmaf(s3.y, wb.y, A31);
            A31 = fmaf(s3.z, wb.z, A31); A31 = fmaf(s3.w, wb.w, A31);
        }
        A00 = fmaf(sb0[48], w0[48], A00); A00 = fmaf(sb0[49], w0[49], A00);
        A01 = fmaf(sb0[48], w1[48], A01); A01 = fmaf(sb0[49], w1[49], A01);
        A10 = fmaf(sb1[48], w0[48], A10); A10 = fmaf(sb1[49], w0[49], A10);
        A11 = fmaf(sb1[48], w1[48], A11); A11 = fmaf(sb1[49], w1[49], A11);
        A20 = fmaf(sb2[48], w0[48], A20); A20 = fmaf(sb2[49], w0[49], A20);
        A21 = fmaf(sb2[48], w1[48], A21); A21 = fmaf(sb2[49], w1[49], A21);
        A30 = fmaf(sb3[48], w0[48], A30); A30 = fmaf(sb3[49], w0[49], A30);
        A31 = fmaf(sb3[48], w1[48], A31); A31 = fmaf(sb3[49], w1[49], A31);
        acur[(t0     ) * 12 + op] = A00;  acur[(t0     ) * 12 + op + 5] = A01;
        acur[(t0 + 31) * 12 + op] = A10;  acur[(t0 + 31) * 12 + op + 5] = A11;
        acur[(t0 + 62) * 12 + op] = A20;  acur[(t0 + 62) * 12 + op + 5] = A21;
        acur[(t0 + 93) * 12 + op] = A30;  acur[(t0 + 93) * 12 + op + 5] = A31;
    }
    __syncthreads();

    // ---- AC membrane chains + output stores: batch-8
    if (tid < OUT_) {
        float mem = 0.0f;
        for (int t0 = 0; t0 < 120; t0 += 8) {
            float c0[8];
#pragma unroll
            for (int k = 0; k < 8; ++k) c0[k] = acur[(t0 + k) * 12 + tid];
#pragma unroll
            for (int k = 0; k < 8; ++k) {
                float m = fadd(fmul(0.95f, mem), c0[k]);
                float sp = (fsub(m, 1.0f) > 0.0f) ? 1.0f : 0.0f;
                float mo = fsub(m, sp);
                mem = mo;
                size_t base = ((size_t)b * T_ + (t0 + k)) * OUT_ + tid;
                out[base] = sp;
                out[(size_t)(B_ * T_ * OUT_) + base] = mo;
            }
        }
        for (int t = 120; t < T_; ++t) {
            float m = fadd(fmul(0.95f, mem), acur[t * 12 + tid]);
            float sp = (fsub(m, 1.0f) > 0.0f) ? 1.0f : 0.0f;
            float mo = fsub(m, sp);
            mem = mo;
            size_t base = ((size_t)b * T_ + t) * OUT_ + tid;
            out[base] = sp;
            out[(size_t)(B_ * T_ * OUT_) + base] = mo;
        }
    }
}

// ---------------------------------------------------------------------------
extern "C" void kernel_launch(void* const* d_in, const int* in_sizes, int n_in,
                              void* d_out, int out_size, void* d_ws, size_t ws_size,
                              hipStream_t stream) {
    (void)in_sizes; (void)n_in; (void)out_size; (void)ws_size;
    const float* audio = (const float*)d_in[0];
    const float* gt    = (const float*)d_in[1];
    const float* Wb    = (const float*)d_in[2];
    const float* Wic   = (const float*)d_in[3];
    const float* Wac   = (const float*)d_in[4];

    float* Sg = (float*)d_ws;   // needs 256*32*125*4 = 4,096,000 B of ws

    convA<<<dim3(B_, 16), dim3(256), 0, stream>>>(audio, gt, Sg);
    snnB<<<dim3(B_), dim3(TB_), 0, stream>>>(Sg, Wb, Wic, Wac, (float*)d_out);
}

// Round 8
// 285.864 us; speedup vs baseline: 1.1052x; 1.0003x over previous
//
#include <hip/hip_runtime.h>

// Problem dims
#define B_   256
#define N_   16000
#define C_   32
#define K_   64
#define T_   124
#define NJ   125      // 128-sample half-window block sums, j = 0..124
#define HID_ 50
#define OUT_ 10
#define TB_  1024     // snnB block size
#define CURS 52       // padded stride for cur/icur (float4-aligned)
#define WBS  324      // sWb row stride (float4-aligned)
#define TSPAN 62      // snnB1 t-slice

typedef unsigned int u32;
typedef float v2f __attribute__((ext_vector_type(2)));
struct __align__(16) f2x2 { v2f lo, hi; };

// Exact single f32 ops (prevent fma contraction / reassociation).
__device__ __forceinline__ float fadd(float a, float b) { return __fadd_rn(a, b); }
__device__ __forceinline__ float fmul(float a, float b) { return __fmul_rn(a, b); }
__device__ __forceinline__ float fsub(float a, float b) { return __fsub_rn(a, b); }

// Packed f32 FMA: y.lo += a.lo*tap, y.hi += a.hi*tap, tap = slot k of pair-pair T,
// broadcast via VOP3P op_sel. T lives in SGPRs (s_load'd, wave-uniform).
__device__ __forceinline__ void PKFMA(v2f& y, v2f a, const f2x2& T, int k) {
    switch (k) {
    case 0:  asm("v_pk_fma_f32 %0, %1, %2, %0 op_sel:[0,0,0] op_sel_hi:[1,0,1]"
                 : "+v"(y) : "v"(a), "s"(T.lo)); break;
    case 1:  asm("v_pk_fma_f32 %0, %1, %2, %0 op_sel:[0,1,0] op_sel_hi:[1,1,1]"
                 : "+v"(y) : "v"(a), "s"(T.lo)); break;
    case 2:  asm("v_pk_fma_f32 %0, %1, %2, %0 op_sel:[0,0,0] op_sel_hi:[1,0,1]"
                 : "+v"(y) : "v"(a), "s"(T.hi)); break;
    default: asm("v_pk_fma_f32 %0, %1, %2, %0 op_sel:[0,1,0] op_sel_hi:[1,1,1]"
                 : "+v"(y) : "v"(a), "s"(T.hi)); break;
    }
}

// ---------------------------------------------------------------------------
// Kernel A: unchanged r21 (best measured 177-184 us, VGPR 52, no spills).
// ---------------------------------------------------------------------------
__global__ __launch_bounds__(256, 4) void convA(const float* __restrict__ audio,
                                                const float* __restrict__ gt,
                                                float* __restrict__ Sg) {
    __shared__ __align__(16) float abI[1280];         //  5,120 B  [P][640] interleaved
    __shared__ __align__(16) float ybuf[4][4][272];   // 17,408 B [wave][ch][2blk*136]

    const int b = blockIdx.x, g = blockIdx.y;
    const int tid = threadIdx.x, w = tid >> 6, lane = tid & 63;
    const float* arow = audio + (size_t)b * N_;

    const int origin = (g << 10) - 32;
    for (int idx = tid; idx < 1280; idx += 256) {
        int P = idx / 640, j = idx - P * 640;
        int ii = j >> 1, h = j & 1;
        int gi = origin + (P << 9) + (h << 8) + ii;
        float v = (gi >= 0 && gi < N_) ? arow[gi] : 0.0f;
        abI[P * 640 + (j ^ (((j >> 5) & 1) << 2))] = v;
    }
    __syncthreads();

    for (int G = 0; G < 2; ++G) {
        const int rowbase = __builtin_amdgcn_readfirstlane(((w << 3) + (G << 2)) << 6);
        const float* kg = gt + rowbase;

        v2f Y[2][4][4];
#pragma unroll
        for (int P = 0; P < 2; ++P)
#pragma unroll
            for (int ch = 0; ch < 4; ++ch)
#pragma unroll
                for (int d = 0; d < 4; ++d) { Y[P][ch][d].x = 0.0f; Y[P][ch][d].y = 0.0f; }

        // ---- q = 0 peel
        {
            f2x2 Tc[4];
#pragma unroll
            for (int ch = 0; ch < 4; ++ch)
                Tc[ch] = *(const f2x2*)(kg + (ch << 6));
            const int u = lane;
            const int p1 = (u << 3) ^ (((u >> 2) & 1) << 2);
#pragma unroll
            for (int P = 0; P < 2; ++P) {
                const float* abP = abI + P * 640;
                const f2x2 A0 = *(const f2x2*)(abP + p1);
                const f2x2 A1 = *(const f2x2*)(abP + (p1 ^ 4));
#pragma unroll
                for (int e = 0; e < 4; ++e) {
                    const v2f a = (e == 0) ? A0.lo : (e == 1) ? A0.hi
                                : (e == 2) ? A1.lo : A1.hi;
#pragma unroll
                    for (int ch = 0; ch < 4; ++ch)
#pragma unroll
                        for (int d = 0; d < 4; ++d) {
                            const int kb = e - 1 - d;
                            if (kb >= 0) PKFMA(Y[P][ch][d], a, Tc[ch], kb);
                        }
                }
            }
        }

        // ---- q = 1..15
#pragma unroll 1
        for (int q = 1; q < 16; ++q) {
            f2x2 Tm[4], Tc[4];
#pragma unroll
            for (int ch = 0; ch < 4; ++ch) {
                Tm[ch] = *(const f2x2*)(kg + (ch << 6) + ((q - 1) << 2));
                Tc[ch] = *(const f2x2*)(kg + (ch << 6) + (q << 2));
            }
            const int u = lane + q;
            const int p1 = (u << 3) ^ (((u >> 2) & 1) << 2);
#pragma unroll
            for (int P = 0; P < 2; ++P) {
                const float* abP = abI + P * 640;
                const f2x2 A0 = *(const f2x2*)(abP + p1);
                const f2x2 A1 = *(const f2x2*)(abP + (p1 ^ 4));
#pragma unroll
                for (int e = 0; e < 4; ++e) {
                    const v2f a = (e == 0) ? A0.lo : (e == 1) ? A0.hi
                                : (e == 2) ? A1.lo : A1.hi;
#pragma unroll
                    for (int ch = 0; ch < 4; ++ch)
#pragma unroll
                        for (int d = 0; d < 4; ++d) {
                            const int ts = e - 1 - d;
                            if (ts >= 0) PKFMA(Y[P][ch][d], a, Tc[ch], ts);
                            else         PKFMA(Y[P][ch][d], a, Tm[ch], 4 + ts);
                        }
                }
            }
        }

        // ---- q = 16 peel
        {
            f2x2 Tm[4];
#pragma unroll
            for (int ch = 0; ch < 4; ++ch)
                Tm[ch] = *(const f2x2*)(kg + (ch << 6) + 60);
            const int u = lane + 16;
            const int p1 = (u << 3) ^ (((u >> 2) & 1) << 2);
#pragma unroll
            for (int P = 0; P < 2; ++P) {
                const float* abP = abI + P * 640;
                const f2x2 A0 = *(const f2x2*)(abP + p1);
                const f2x2 A1 = *(const f2x2*)(abP + (p1 ^ 4));
#pragma unroll
                for (int e = 0; e < 4; ++e) {
                    const v2f a = (e == 0) ? A0.lo : (e == 1) ? A0.hi
                                : (e == 2) ? A1.lo : A1.hi;
#pragma unroll
                    for (int ch = 0; ch < 4; ++ch)
#pragma unroll
                        for (int d = 0; d < 4; ++d) {
                            const int ts = e - 1 - d;
                            if (ts < 0) PKFMA(Y[P][ch][d], a, Tm[ch], 4 + ts);
                        }
                }
            }
        }

        // ---- epilogue per pp
#pragma unroll
        for (int pp = 0; pp < 4; ++pp) {
            const int P = pp >> 1, h = pp & 1;
#pragma unroll
            for (int ch = 0; ch < 4; ++ch) {
                float4 z;
                z.x = fmaxf(h ? Y[P][ch][0].y : Y[P][ch][0].x, 0.0f);
                z.y = fmaxf(h ? Y[P][ch][1].y : Y[P][ch][1].x, 0.0f);
                z.z = fmaxf(h ? Y[P][ch][2].y : Y[P][ch][2].x, 0.0f);
                z.w = fmaxf(h ? Y[P][ch][3].y : Y[P][ch][3].x, 0.0f);
                *(float4*)(&ybuf[w][ch][((lane >> 5) * 136) + ((lane & 31) << 2)]) = z;
            }
            {
                const int ch2 = lane >> 4, blk = (lane >> 3) & 1, j = lane & 7;
                const float* yb = &ybuf[w][ch2][blk * 136 + j];
                float r = yb[0];
#pragma unroll
                for (int m = 1; m < 16; ++m) r = fadd(r, yb[m << 3]);
                float v = fadd(r, __shfl_xor(r, 1));
                v = fadd(v, __shfl_xor(v, 2));
                v = fadd(v, __shfl_xor(v, 4));
                const int jg = (g << 3) + (pp << 1) + blk;
                const int c = (w << 3) + (G << 2) + ch2;
                if (j == 0 && jg < NJ) Sg[((size_t)b * C_ + c) * NJ + jg] = v;
            }
        }
    }
}

// ---------------------------------------------------------------------------
// snnB1 (ROUND-22): masks + bushy currents, t-sliced. grid (256 b, 2 tg),
// 2 blocks/CU (LDS 67 KB): 2x wave parallelism on the dominant phase vs the
// single-block snnB. Thread (tl in 31, hp in 25): t = tbase+tl, tbase+31+tl;
// h = hp, hp+25. Per-output i-ascending chains (sbfe+and+pk_add halves, each
// IEEE fadd of +0.0/w) identical to r21: bit-exact. Writes raw currents to
// cur2[b][t][h] in workspace.
// ---------------------------------------------------------------------------
__global__ __launch_bounds__(1024, 8) void snnB1(const float* __restrict__ Sg,
                                                 const float* __restrict__ Wb,
                                                 float* __restrict__ cur2) {
    __shared__ __align__(16) float sWb[HID_ * WBS];   // 64,800 B
    __shared__ u32 mask[64 * 10];                     //  2,560 B (62 rows used)

    const int b = blockIdx.x, tg = blockIdx.y;
    const int tid = threadIdx.x;
    const int tbase = tg * TSPAN;

    // sWb: float4 staging (320 % 4 == 0 -> each float4 within one row)
    for (int i4 = tid; i4 < 4000; i4 += 1024) {
        const int i = i4 << 2;
        const int r = i / 320, col = i - r * 320;
        *(float4*)(&sWb[r * WBS + col]) = *(const float4*)(Wb + i);
    }

    // masks for t in [tbase, tbase+62)  (identical expressions to r21)
    const float* Sb = Sg + (size_t)b * C_ * NJ;
    for (int idx = tid; idx < 640; idx += 1024) {
        if (idx >= TSPAN * 10) { mask[idx] = 0; continue; }
        int tl = idx / 10, wd = idx - tl * 10;
        int t = tbase + tl;
        u32 m = 0;
        int c_prev = -1;
        float env = 0.0f;
        for (int k = 0; k < 32; ++k) {
            int i = wd * 32 + k;
            int c = i / 10, s = i - c * 10;
            if (c != c_prev) {
                env = fmul(fadd(Sb[c * NJ + t], Sb[c * NJ + t + 1]), 0.00390625f);
                c_prev = c;
            }
            float sf = (s == 9) ? 1.5f : (float)(0.5 + (double)s * (1.0 / 9.0));
            if (fsub(fmul(env, sf), 0.5f) > 0.0f) m |= (1u << k);
        }
        mask[idx] = m;
    }
    __syncthreads();

    // bushy currents: t-pair (tl, tl+31) x h-pair (hp, hp+25)
    if (tid < 31 * 25) {
        const int tl = tid / 25, hp = tid - tl * 25;
        const float* wr0 = sWb + hp * WBS;
        const float* wr1 = sWb + (hp + 25) * WBS;
        const u32* mA = mask + tl * 10;
        const u32* mB = mask + (tl + 31) * 10;
        v2f A0 = {0.0f, 0.0f}, A1 = {0.0f, 0.0f};  // x = h=hp, y = h=hp+25
#pragma unroll 1
        for (int wi = 0; wi < 10; ++wi) {
            const u32 wa = mA[wi], wc = mB[wi];
#pragma unroll
            for (int b2 = 0; b2 < 32; ++b2) {
                const int i = (wi << 5) + b2;
                const int iw0 = __float_as_int(wr0[i]);
                const int iw1 = __float_as_int(wr1[i]);
                const int sa = __builtin_amdgcn_sbfe((int)wa, b2, 1);
                const int sc = __builtin_amdgcn_sbfe((int)wc, b2, 1);
                v2f p0, p1;
                p0.x = __int_as_float(iw0 & sa);  p0.y = __int_as_float(iw1 & sa);
                p1.x = __int_as_float(iw0 & sc);  p1.y = __int_as_float(iw1 & sc);
                A0 = A0 + p0;   // v_pk_add_f32: each half IEEE fadd
                A1 = A1 + p1;
            }
        }
        float* cb = cur2 + ((size_t)b * T_ + tbase) * HID_;
        cb[(tl     ) * HID_ + hp] = A0.x;  cb[(tl     ) * HID_ + hp + 25] = A0.y;
        cb[(tl + 31) * HID_ + hp] = A1.x;  cb[(tl + 31) * HID_ + hp + 25] = A1.y;
    }
}

// ---------------------------------------------------------------------------
// snnB2 (ROUND-22): membranes + IC + AC per b. Stages cur2 -> LDS, then runs
// the EXACT r21 phase code (bit-exact).
// ---------------------------------------------------------------------------
__global__ __launch_bounds__(1024, 1) void snnB2(const float* __restrict__ cur2,
                                                 const float* __restrict__ Wic,
                                                 const float* __restrict__ Wac,
                                                 float* __restrict__ out) {
    __shared__ __align__(16) float sWic[HID_ * 52];   // 10,400 B
    __shared__ __align__(16) float sWac[OUT_ * 52];   //  2,080 B
    __shared__ __align__(16) float cur[T_ * CURS];    // 25,792 B
    __shared__ __align__(16) float icur[T_ * CURS];   // 25,792 B
    __shared__ float acur[T_ * 12];                   //  5,952 B  (~70 KB)

    const int b = blockIdx.x, tid = threadIdx.x;

    for (int i = tid; i < HID_ * HID_; i += 1024) {
        int r = i / 50;
        sWic[r * 52 + (i - r * 50)] = Wic[i];
    }
    for (int i = tid; i < OUT_ * HID_; i += 1024) {
        int r = i / 50;
        sWac[r * 52 + (i - r * 50)] = Wac[i];
    }
    // stage currents: float2 (50 even: pairs never cross a t-row)
    const float* cb = cur2 + (size_t)b * T_ * HID_;
    for (int j = tid; j < T_ * 25; j += 1024) {
        int t = j / 25, h2 = (j - t * 25) << 1;
        *(float2*)(&cur[t * CURS + h2]) = *(const float2*)(cb + t * HID_ + h2);
    }
    __syncthreads();

    // ---- Bushy membrane chains: batch-8 (exact r21)
    if (tid < HID_) {
        float mem = 0.0f;
        for (int t0 = 0; t0 < 120; t0 += 8) {
            float c0[8];
#pragma unroll
            for (int k = 0; k < 8; ++k) c0[k] = cur[(t0 + k) * CURS + tid];
#pragma unroll
            for (int k = 0; k < 8; ++k) {
                float m = fadd(fmul(0.95f, mem), c0[k]);
                float sp = (fsub(m, 1.0f) > 0.0f) ? 1.0f : 0.0f;
                mem = fsub(m, sp);
                cur[(t0 + k) * CURS + tid] = sp;
            }
        }
        for (int t = 120; t < T_; ++t) {
            float m = fadd(fmul(0.95f, mem), cur[t * CURS + tid]);
            float sp = (fsub(m, 1.0f) > 0.0f) ? 1.0f : 0.0f;
            mem = fsub(m, sp);
            cur[t * CURS + tid] = sp;
        }
    }
    __syncthreads();

    // ---- IC currents: t-quad x h-pair, g4-outer (exact r21)
    if (tid < 31 * 25) {
        const int t0 = tid / 25, hp = tid - t0 * 25;
        const float* w0 = sWic + hp * 52;
        const float* w1 = sWic + (hp + 25) * 52;
        const float* sb0 = cur + (t0     ) * CURS;
        const float* sb1 = cur + (t0 + 31) * CURS;
        const float* sb2 = cur + (t0 + 62) * CURS;
        const float* sb3 = cur + (t0 + 93) * CURS;
        float A00 = 0.0f, A01 = 0.0f, A10 = 0.0f, A11 = 0.0f;
        float A20 = 0.0f, A21 = 0.0f, A30 = 0.0f, A31 = 0.0f;
#pragma unroll
        for (int g4 = 0; g4 < 12; ++g4) {
            const float4 wa = *(const float4*)(w0 + (g4 << 2));
            const float4 wb = *(const float4*)(w1 + (g4 << 2));
            const float4 s0 = *(const float4*)(sb0 + (g4 << 2));
            const float4 s1 = *(const float4*)(sb1 + (g4 << 2));
            const float4 s2 = *(const float4*)(sb2 + (g4 << 2));
            const float4 s3 = *(const float4*)(sb3 + (g4 << 2));
            A00 = fmaf(s0.x, wa.x, A00); A00 = fmaf(s0.y, wa.y, A00);
            A00 = fmaf(s0.z, wa.z, A00); A00 = fmaf(s0.w, wa.w, A00);
            A01 = fmaf(s0.x, wb.x, A01); A01 = fmaf(s0.y, wb.y, A01);
            A01 = fmaf(s0.z, wb.z, A01); A01 = fmaf(s0.w, wb.w, A01);
            A10 = fmaf(s1.x, wa.x, A10); A10 = fmaf(s1.y, wa.y, A10);
            A10 = fmaf(s1.z, wa.z, A10); A10 = fmaf(s1.w, wa.w, A10);
            A11 = fmaf(s1.x, wb.x, A11); A11 = fmaf(s1.y, wb.y, A11);
            A11 = fmaf(s1.z, wb.z, A11); A11 = fmaf(s1.w, wb.w, A11);
            A20 = fmaf(s2.x, wa.x, A20); A20 = fmaf(s2.y, wa.y, A20);
            A20 = fmaf(s2.z, wa.z, A20); A20 = fmaf(s2.w, wa.w, A20);
            A21 = fmaf(s2.x, wb.x, A21); A21 = fmaf(s2.y, wb.y, A21);
            A21 = fmaf(s2.z, wb.z, A21); A21 = fmaf(s2.w, wb.w, A21);
            A30 = fmaf(s3.x, wa.x, A30); A30 = fmaf(s3.y, wa.y, A30);
            A30 = fmaf(s3.z, wa.z, A30); A30 = fmaf(s3.w, wa.w, A30);
            A31 = fmaf(s3.x, wb.x, A31); A31 = fmaf(s3.y, wb.y, A31);
            A31 = fmaf(s3.z, wb.z, A31); A31 = fmaf(s3.w, wb.w, A31);
        }
        A00 = fmaf(sb0[48], w0[48], A00); A00 = fmaf(sb0[49], w0[49], A00);
        A01 = fmaf(sb0[48], w1[48], A01); A01 = fmaf(sb0[49], w1[49], A01);
        A10 = fmaf(sb1[48], w0[48], A10); A10 = fmaf(sb1[49], w0[49], A10);
        A11 = fmaf(sb1[48], w1[48], A11); A11 = fmaf(sb1[49], w1[49], A11);
        A20 = fmaf(sb2[48], w0[48], A20); A20 = fmaf(sb2[49], w0[49], A20);
        A21 = fmaf(sb2[48], w1[48], A21); A21 = fmaf(sb2[49], w1[49], A21);
        A30 = fmaf(sb3[48], w0[48], A30); A30 = fmaf(sb3[49], w0[49], A30);
        A31 = fmaf(sb3[48], w1[48], A31); A31 = fmaf(sb3[49], w1[49], A31);
        icur[(t0     ) * CURS + hp] = A00;  icur[(t0     ) * CURS + hp + 25] = A01;
        icur[(t0 + 31) * CURS + hp] = A10;  icur[(t0 + 31) * CURS + hp + 25] = A11;
        icur[(t0 + 62) * CURS + hp] = A20;  icur[(t0 + 62) * CURS + hp + 25] = A21;
        icur[(t0 + 93) * CURS + hp] = A30;  icur[(t0 + 93) * CURS + hp + 25] = A31;
    }
    __syncthreads();

    // ---- IC membrane chains: batch-8 (exact r21)
    if (tid < HID_) {
        float mem = 0.0f;
        for (int t0 = 0; t0 < 120; t0 += 8) {
            float c0[8];
#pragma unroll
            for (int k = 0; k < 8; ++k) c0[k] = icur[(t0 + k) * CURS + tid];
#pragma unroll
            for (int k = 0; k < 8; ++k) {
                float m = fadd(fmul(0.95f, mem), c0[k]);
                float sp = (fsub(m, 1.0f) > 0.0f) ? 1.0f : 0.0f;
                mem = fsub(m, sp);
                icur[(t0 + k) * CURS + tid] = sp;
            }
        }
        for (int t = 120; t < T_; ++t) {
            float m = fadd(fmul(0.95f, mem), icur[t * CURS + tid]);
            float sp = (fsub(m, 1.0f) > 0.0f) ? 1.0f : 0.0f;
            mem = fsub(m, sp);
            icur[t * CURS + tid] = sp;
        }
    }
    __syncthreads();

    // ---- AC currents: t-quad x o-pair (exact r21)
    if (tid < 31 * 5) {
        const int t0 = tid / 5, op = tid - t0 * 5;
        const float* w0 = sWac + op * 52;
        const float* w1 = sWac + (op + 5) * 52;
        const float* sb0 = icur + (t0     ) * CURS;
        const float* sb1 = icur + (t0 + 31) * CURS;
        const float* sb2 = icur + (t0 + 62) * CURS;
        const float* sb3 = icur + (t0 + 93) * CURS;
        float A00 = 0.0f, A01 = 0.0f, A10 = 0.0f, A11 = 0.0f;
        float A20 = 0.0f, A21 = 0.0f, A30 = 0.0f, A31 = 0.0f;
#pragma unroll
        for (int g4 = 0; g4 < 12; ++g4) {
            const float4 wa = *(const float4*)(w0 + (g4 << 2));
            const float4 wb = *(const float4*)(w1 + (g4 << 2));
            const float4 s0 = *(const float4*)(sb0 + (g4 << 2));
            const float4 s1 = *(const float4*)(sb1 + (g4 << 2));
            const float4 s2 = *(const float4*)(sb2 + (g4 << 2));
            const float4 s3 = *(const float4*)(sb3 + (g4 << 2));
            A00 = fmaf(s0.x, wa.x, A00); A00 = fmaf(s0.y, wa.y, A00);
            A00 = fmaf(s0.z, wa.z, A00); A00 = fmaf(s0.w, wa.w, A00);
            A01 = fmaf(s0.x, wb.x, A01); A01 = fmaf(s0.y, wb.y, A01);
            A01 = fmaf(s0.z, wb.z, A01); A01 = fmaf(s0.w, wb.w, A01);
            A10 = fmaf(s1.x, wa.x, A10); A10 = fmaf(s1.y, wa.y, A10);
            A10 = fmaf(s1.z, wa.z, A10); A10 = fmaf(s1.w, wa.w, A10);
            A11 = fmaf(s1.x, wb.x, A11); A11 = fmaf(s1.y, wb.y, A11);
            A11 = fmaf(s1.z, wb.z, A11); A11 = fmaf(s1.w, wb.w, A11);
            A20 = fmaf(s2.x, wa.x, A20); A20 = fmaf(s2.y, wa.y, A20);
            A20 = fmaf(s2.z, wa.z, A20); A20 = fmaf(s2.w, wa.w, A20);
            A21 = fmaf(s2.x, wb.x, A21); A21 = fmaf(s2.y, wb.y, A21);
            A21 = fmaf(s2.z, wb.z, A21); A21 = fmaf(s2.w, wb.w, A21);
            A30 = fmaf(s3.x, wa.x, A30); A30 = fmaf(s3.y, wa.y, A30);
            A30 = fmaf(s3.z, wa.z, A30); A30 = fmaf(s3.w, wa.w, A30);
            A31 = fmaf(s3.x, wb.x, A31); A31 = fmaf(s3.y, wb.y, A31);
            A31 = fmaf(s3.z, wb.z, A31); A31 = fmaf(s3.w, wb.w, A31);
        }
        A00 = fmaf(sb0[48], w0[48], A00); A00 = fmaf(sb0[49], w0[49], A00);
        A01 = fmaf(sb0[48], w1[48], A01); A01 = fmaf(sb0[49], w1[49], A01);
        A10 = fmaf(sb1[48], w0[48], A10); A10 = fmaf(sb1[49], w0[49], A10);
        A11 = fmaf(sb1[48], w1[48], A11); A11 = fmaf(sb1[49], w1[49], A11);
        A20 = fmaf(sb2[48], w0[48], A20); A20 = fmaf(sb2[49], w0[49], A20);
        A21 = fmaf(sb2[48], w1[48], A21); A21 = fmaf(sb2[49], w1[49], A21);
        A30 = fmaf(sb3[48], w0[48], A30); A30 = fmaf(sb3[49], w0[49], A30);
        A31 = fmaf(sb3[48], w1[48], A31); A31 = fmaf(sb3[49], w1[49], A31);
        acur[(t0     ) * 12 + op] = A00;  acur[(t0     ) * 12 + op + 5] = A01;
        acur[(t0 + 31) * 12 + op] = A10;  acur[(t0 + 31) * 12 + op + 5] = A11;
        acur[(t0 + 62) * 12 + op] = A20;  acur[(t0 + 62) * 12 + op + 5] = A21;
        acur[(t0 + 93) * 12 + op] = A30;  acur[(t0 + 93) * 12 + op + 5] = A31;
    }
    __syncthreads();

    // ---- AC membrane chains + output stores: batch-8 (exact r21)
    if (tid < OUT_) {
        float mem = 0.0f;
        for (int t0 = 0; t0 < 120; t0 += 8) {
            float c0[8];
#pragma unroll
            for (int k = 0; k < 8; ++k) c0[k] = acur[(t0 + k) * 12 + tid];
#pragma unroll
            for (int k = 0; k < 8; ++k) {
                float m = fadd(fmul(0.95f, mem), c0[k]);
                float sp = (fsub(m, 1.0f) > 0.0f) ? 1.0f : 0.0f;
                float mo = fsub(m, sp);
                mem = mo;
                size_t base = ((size_t)b * T_ + (t0 + k)) * OUT_ + tid;
                out[base] = sp;
                out[(size_t)(B_ * T_ * OUT_) + base] = mo;
            }
        }
        for (int t = 120; t < T_; ++t) {
            float m = fadd(fmul(0.95f, mem), acur[t * 12 + tid]);
            float sp = (fsub(m, 1.0f) > 0.0f) ? 1.0f : 0.0f;
            float mo = fsub(m, sp);
            mem = mo;
            size_t base = ((size_t)b * T_ + t) * OUT_ + tid;
            out[base] = sp;
            out[(size_t)(B_ * T_ * OUT_) + base] = mo;
        }
    }
}

// ---------------------------------------------------------------------------
// Fallback: r21 single-kernel snnB (used only if ws too small for cur2).
// ---------------------------------------------------------------------------
__global__ __launch_bounds__(TB_, 1) void snnB(const float* __restrict__ Sg,
                                               const float* __restrict__ Wb,
                                               const float* __restrict__ Wic,
                                               const float* __restrict__ Wac,
                                               float* __restrict__ out) {
    __shared__ __align__(16) float sWb[HID_ * WBS];
    __shared__ __align__(16) float sWic[HID_ * 52];
    __shared__ __align__(16) float sWac[OUT_ * 52];
    __shared__ u32   mask[128 * 10];
    __shared__ __align__(16) float cur[T_ * CURS];
    __shared__ __align__(16) float icur[T_ * CURS];
    __shared__ float acur[T_ * 12];

    const int b = blockIdx.x, tid = threadIdx.x;

    for (int i4 = tid; i4 < 4000; i4 += TB_) {
        const int i = i4 << 2;
        const int r = i / 320, col = i - r * 320;
        *(float4*)(&sWb[r * WBS + col]) = *(const float4*)(Wb + i);
    }
    for (int i = tid; i < HID_ * HID_; i += TB_) {
        int r = i / 50;
        sWic[r * 52 + (i - r * 50)] = Wic[i];
    }
    for (int i = tid; i < OUT_ * HID_; i += TB_) {
        int r = i / 50;
        sWac[r * 52 + (i - r * 50)] = Wac[i];
    }

    const float* Sb = Sg + (size_t)b * C_ * NJ;
    for (int idx = tid; idx < 1280; idx += TB_) {
        if (idx >= T_ * 10) { mask[idx] = 0; continue; }
        int t = idx / 10, wd = idx - t * 10;
        u32 m = 0;
        int c_prev = -1;
        float env = 0.0f;
        for (int k = 0; k < 32; ++k) {
            int i = wd * 32 + k;
            int c = i / 10, s = i - c * 10;
            if (c != c_prev) {
                env = fmul(fadd(Sb[c * NJ + t], Sb[c * NJ + t + 1]), 0.00390625f);
                c_prev = c;
            }
            float sf = (s == 9) ? 1.5f : (float)(0.5 + (double)s * (1.0 / 9.0));
            if (fsub(fmul(env, sf), 0.5f) > 0.0f) m |= (1u << k);
        }
        mask[idx] = m;
    }
    __syncthreads();

    if (tid < 31 * 25) {
        const int t0 = tid / 25, hp = tid - t0 * 25;
        const float* wr0 = sWb + hp * WBS;
        const float* wr1 = sWb + (hp + 25) * WBS;
        const u32* mrow = mask + t0 * 10;
        v2f a0 = {0.0f, 0.0f}, a1 = {0.0f, 0.0f};
        v2f a2 = {0.0f, 0.0f}, a3 = {0.0f, 0.0f};
#pragma unroll 1
        for (int wi = 0; wi < 10; ++wi) {
            const u32 w0 = mrow[wi],       w1 = mrow[310 + wi];
            const u32 w2 = mrow[620 + wi], w3 = mrow[930 + wi];
#pragma unroll
            for (int b2 = 0; b2 < 32; ++b2) {
                const int i = (wi << 5) + b2;
                const int iw0 = __float_as_int(wr0[i]);
                const int iw1 = __float_as_int(wr1[i]);
                const int s0 = __builtin_amdgcn_sbfe((int)w0, b2, 1);
                const int s1 = __builtin_amdgcn_sbfe((int)w1, b2, 1);
                const int s2 = __builtin_amdgcn_sbfe((int)w2, b2, 1);
                const int s3 = __builtin_amdgcn_sbfe((int)w3, b2, 1);
                v2f p0, p1, p2, p3;
                p0.x = __int_as_float(iw0 & s0);  p0.y = __int_as_float(iw1 & s0);
                p1.x = __int_as_float(iw0 & s1);  p1.y = __int_as_float(iw1 & s1);
                p2.x = __int_as_float(iw0 & s2);  p2.y = __int_as_float(iw1 & s2);
                p3.x = __int_as_float(iw0 & s3);  p3.y = __int_as_float(iw1 & s3);
                a0 = a0 + p0;
                a1 = a1 + p1;
                a2 = a2 + p2;
                a3 = a3 + p3;
            }
        }
        cur[(t0     ) * CURS + hp] = a0.x;  cur[(t0     ) * CURS + hp + 25] = a0.y;
        cur[(t0 + 31) * CURS + hp] = a1.x;  cur[(t0 + 31) * CURS + hp + 25] = a1.y;
        cur[(t0 + 62) * CURS + hp] = a2.x;  cur[(t0 + 62) * CURS + hp + 25] = a2.y;
        cur[(t0 + 93) * CURS + hp] = a3.x;  cur[(t0 + 93) * CURS + hp + 25] = a3.y;
    }
    __syncthreads();

    if (tid < HID_) {
        float mem = 0.0f;
        for (int t0 = 0; t0 < 120; t0 += 8) {
            float c0[8];
#pragma unroll
            for (int k = 0; k < 8; ++k) c0[k] = cur[(t0 + k) * CURS + tid];
#pragma unroll
            for (int k = 0; k < 8; ++k) {
                float m = fadd(fmul(0.95f, mem), c0[k]);
                float sp = (fsub(m, 1.0f) > 0.0f) ? 1.0f : 0.0f;
                mem = fsub(m, sp);
                cur[(t0 + k) * CURS + tid] = sp;
            }
        }
        for (int t = 120; t < T_; ++t) {
            float m = fadd(fmul(0.95f, mem), cur[t * CURS + tid]);
            float sp = (fsub(m, 1.0f) > 0.0f) ? 1.0f : 0.0f;
            mem = fsub(m, sp);
            cur[t * CURS + tid] = sp;
        }
    }
    __syncthreads();

    if (tid < 31 * 25) {
        const int t0 = tid / 25, hp = tid - t0 * 25;
        const float* w0 = sWic + hp * 52;
        const float* w1 = sWic + (hp + 25) * 52;
        const float* sb0 = cur + (t0     ) * CURS;
        const float* sb1 = cur + (t0 + 31) * CURS;
        const float* sb2 = cur + (t0 + 62) * CURS;
        const float* sb3 = cur + (t0 + 93) * CURS;
        float A00 = 0.0f, A01 = 0.0f, A10 = 0.0f, A11 = 0.0f;
        float A20 = 0.0f, A21 = 0.0f, A30 = 0.0f, A31 = 0.0f;
#pragma unroll
        for (int g4 = 0; g4 < 12; ++g4) {
            const float4 wa = *(const float4*)(w0 + (g4 << 2));
            const float4 wb = *(const float4*)(w1 + (g4 << 2));
            const float4 s0 = *(const float4*)(sb0 + (g4 << 2));
            const float4 s1 = *(const float4*)(sb1 + (g4 << 2));
            const float4 s2 = *(const float4*)(sb2 + (g4 << 2));
            const float4 s3 = *(const float4*)(sb3 + (g4 << 2));
            A00 = fmaf(s0.x, wa.x, A00); A00 = fmaf(s0.y, wa.y, A00);
            A00 = fmaf(s0.z, wa.z, A00); A00 = fmaf(s0.w, wa.w, A00);
            A01 = fmaf(s0.x, wb.x, A01); A01 = fmaf(s0.y, wb.y, A01);
            A01 = fmaf(s0.z, wb.z, A01); A01 = fmaf(s0.w, wb.w, A01);
            A10 = fmaf(s1.x, wa.x, A10); A10 = fmaf(s1.y, wa.y, A10);
            A10 = fmaf(s1.z, wa.z, A10); A10 = fmaf(s1.w, wa.w, A10);
            A11 = fmaf(s1.x, wb.x, A11); A11 = fmaf(s1.y, wb.y, A11);
            A11 = fmaf(s1.z, wb.z, A11); A11 = fmaf(s1.w, wb.w, A11);
            A20 = fmaf(s2.x, wa.x, A20); A20 = fmaf(s2.y, wa.y, A20);
            A20 = fmaf(s2.z, wa.z, A20); A20 = fmaf(s2.w, wa.w, A20);
            A21 = fmaf(s2.x, wb.x, A21); A21 = fmaf(s2.y, wb.y, A21);
            A21 = fmaf(s2.z, wb.z, A21); A21 = fmaf(s2.w, wb.w, A21);
            A30 = fmaf(s3.x, wa.x, A30); A30 = fmaf(s3.y, wa.y, A30);
            A30 = fmaf(s3.z, wa.z, A30); A30 = fmaf(s3.w, wa.w, A30);
            A31 = fmaf(s3.x, wb.x, A31); A31 = fmaf(s3.y, wb.y, A31);
            A31 = fmaf(s3.z, wb.z, A31); A31 = fmaf(s3.w, wb.w, A31);
        }
        A00 = fmaf(sb0[48], w0[48], A00); A00 = fmaf(sb0[49], w0[49], A00);
        A01 = fmaf(sb0[48], w1[48], A01); A01 = fmaf(sb0[49], w1[49], A01);
        A10 = fmaf(sb1[48], w0[48], A10); A10 = fmaf(sb1[49], w0[49], A10);
        A11 = fmaf(sb1[48], w1[48], A11); A11 = fmaf(sb1[49], w1[49], A11);
        A20 = fmaf(sb2[48], w0[48], A20); A20 = fmaf(sb2[49], w0[49], A20);
        A21 = fmaf(sb2[48], w1[48], A21); A21 = fmaf(sb2[49], w1[49], A21);
        A30 = fmaf(sb3[48], w0[48], A30); A30 = fmaf(sb3[49], w0[49], A30);
        A31 = fmaf(sb3[48], w1[48], A31); A31 = fmaf(sb3[49], w1[49], A31);
        icur[(t0     ) * CURS + hp] = A00;  icur[(t0     ) * CURS + hp + 25] = A01;
        icur[(t0 + 31) * CURS + hp] = A10;  icur[(t0 + 31) * CURS + hp + 25] = A11;
        icur[(t0 + 62) * CURS + hp] = A20;  icur[(t0 + 62) * CURS + hp + 25] = A21;
        icur[(t0 + 93) * CURS + hp] = A30;  icur[(t0 + 93) * CURS + hp + 25] = A31;
    }
    __syncthreads();

    if (tid < HID_) {
        float mem = 0.0f;
        for (int t0 = 0; t0 < 120; t0 += 8) {
            float c0[8];
#pragma unroll
            for (int k = 0; k < 8; ++k) c0[k] = icur[(t0 + k) * CURS + tid];
#pragma unroll
            for (int k = 0; k < 8; ++k) {
                float m = fadd(fmul(0.95f, mem), c0[k]);
                float sp = (fsub(m, 1.0f) > 0.0f) ? 1.0f : 0.0f;
                mem = fsub(m, sp);
                icur[(t0 + k) * CURS + tid] = sp;
            }
        }
        for (int t = 120; t < T_; ++t) {
            float m = fadd(fmul(0.95f, mem), icur[t * CURS + tid]);
            float sp = (fsub(m, 1.0f) > 0.0f) ? 1.0f : 0.0f;
            mem = fsub(m, sp);
            icur[t * CURS + tid] = sp;
        }
    }
    __syncthreads();

    if (tid < 31 * 5) {
        const int t0 = tid / 5, op = tid - t0 * 5;
        const float* w0 = sWac + op * 52;
        const float* w1 = sWac + (op + 5) * 52;
        const float* sb0 = icur + (t0     ) * CURS;
        const float* sb1 = icur + (t0 + 31) * CURS;
        const float* sb2 = icur + (t0 + 62) * CURS;
        const float* sb3 = icur + (t0 + 93) * CURS;
        float A00 = 0.0f, A01 = 0.0f, A10 = 0.0f, A11 = 0.0f;
        float A20 = 0.0f, A21 = 0.0f, A30 = 0.0f, A31 = 0.0f;
#pragma unroll
        for (int g4 = 0; g4 < 12; ++g4) {
            const float4 wa = *(const float4*)(w0 + (g4 << 2));
            const float4 wb = *(const float4*)(w1 + (g4 << 2));
            const float4 s0 = *(const float4*)(sb0 + (g4 << 2));
            const float4 s1 = *(const float4*)(sb1 + (g4 << 2));
            const float4 s2 = *(const float4*)(sb2 + (g4 << 2));
            const float4 s3 = *(const float4*)(sb3 + (g4 << 2));
            A00 = fmaf(s0.x, wa.x, A00); A00 = fmaf(s0.y, wa.y, A00);
            A00 = fmaf(s0.z, wa.z, A00); A00 = fmaf(s0.w, wa.w, A00);
            A01 = fmaf(s0.x, wb.x, A01); A01 = fmaf(s0.y, wb.y, A01);
            A01 = fmaf(s0.z, wb.z, A01); A01 = fmaf(s0.w, wb.w, A01);
            A10 = fmaf(s1.x, wa.x, A10); A10 = fmaf(s1.y, wa.y, A10);
            A10 = fmaf(s1.z, wa.z, A10); A10 = fmaf(s1.w, wa.w, A10);
            A11 = fmaf(s1.x, wb.x, A11); A11 = fmaf(s1.y, wb.y, A11);
            A11 = fmaf(s1.z, wb.z, A11); A11 = fmaf(s1.w, wb.w, A11);
            A20 = fmaf(s2.x, wa.x, A20); A20 = fmaf(s2.y, wa.y, A20);
            A20 = fmaf(s2.z, wa.z, A20); A20 = fmaf(s2.w, wa.w, A20);
            A21 = fmaf(s2.x, wb.x, A21); A21 = fmaf(s2.y, wb.y, A21);
            A21 = fmaf(s2.z, wb.z, A21); A21 = fmaf(s2.w, wb.w, A21);
            A30 = fmaf(s3.x, wa.x, A30); A30 = fmaf(s3.y, wa.y, A30);
            A30 = fmaf(s3.z, wa.z, A30); A30 = fmaf(s3.w, wa.w, A30);
            A31 = fmaf(s3.x, wb.x, A31); A31 = fmaf(s3.y, wb.y, A31);
            A31 = fmaf(s3.z, wb.z, A31); A31 = fmaf(s3.w, wb.w, A31);
        }
        A00 = fmaf(sb0[48], w0[48], A00); A00 = fmaf(sb0[49], w0[49], A00);
        A01 = fmaf(sb0[48], w1[48], A01); A01 = fmaf(sb0[49], w1[49], A01);
        A10 = fmaf(sb1[48], w0[48], A10); A10 = fmaf(sb1[49], w0[49], A10);
        A11 = fmaf(sb1[48], w1[48], A11); A11 = fmaf(sb1[49], w1[49], A11);
        A20 = fmaf(sb2[48], w0[48], A20); A20 = fmaf(sb2[49], w0[49], A20);
        A21 = fmaf(sb2[48], w1[48], A21); A21 = fmaf(sb2[49], w1[49], A21);
        A30 = fmaf(sb3[48], w0[48], A30); A30 = fmaf(sb3[49], w0[49], A30);
        A31 = fmaf(sb3[48], w1[48], A31); A31 = fmaf(sb3[49], w1[49], A31);
        acur[(t0     ) * 12 + op] = A00;  acur[(t0     ) * 12 + op + 5] = A01;
        acur[(t0 + 31) * 12 + op] = A10;  acur[(t0 + 31) * 12 + op + 5] = A11;
        acur[(t0 + 62) * 12 + op] = A20;  acur[(t0 + 62) * 12 + op + 5] = A21;
        acur[(t0 + 93) * 12 + op] = A30;  acur[(t0 + 93) * 12 + op + 5] = A31;
    }
    __syncthreads();

    if (tid < OUT_) {
        float mem = 0.0f;
        for (int t0 = 0; t0 < 120; t0 += 8) {
            float c0[8];
#pragma unroll
            for (int k = 0; k < 8; ++k) c0[k] = acur[(t0 + k) * 12 + tid];
#pragma unroll
            for (int k = 0; k < 8; ++k) {
                float m = fadd(fmul(0.95f, mem), c0[k]);
                float sp = (fsub(m, 1.0f) > 0.0f) ? 1.0f : 0.0f;
                float mo = fsub(m, sp);
                mem = mo;
                size_t base = ((size_t)b * T_ + (t0 + k)) * OUT_ + tid;
                out[base] = sp;
                out[(size_t)(B_ * T_ * OUT_) + base] = mo;
            }
        }
        for (int t = 120; t < T_; ++t) {
            float m = fadd(fmul(0.95f, mem), acur[t * 12 + tid]);
            float sp = (fsub(m, 1.0f) > 0.0f) ? 1.0f : 0.0f;
            float mo = fsub(m, sp);
            mem = mo;
            size_t base = ((size_t)b * T_ + t) * OUT_ + tid;
            out[base] = sp;
            out[(size_t)(B_ * T_ * OUT_) + base] = mo;
        }
    }
}

// ---------------------------------------------------------------------------
extern "C" void kernel_launch(void* const* d_in, const int* in_sizes, int n_in,
                              void* d_out, int out_size, void* d_ws, size_t ws_size,
                              hipStream_t stream) {
    (void)in_sizes; (void)n_in; (void)out_size;
    const float* audio = (const float*)d_in[0];
    const float* gt    = (const float*)d_in[1];
    const float* Wb    = (const float*)d_in[2];
    const float* Wic   = (const float*)d_in[3];
    const float* Wac   = (const float*)d_in[4];

    float* Sg = (float*)d_ws;                       // 4,096,000 B
    const size_t SG_BYTES  = (size_t)B_ * C_ * NJ * 4;            // 4,096,000
    const size_t CUR_BYTES = (size_t)B_ * T_ * HID_ * 4;          // 6,348,800

    convA<<<dim3(B_, 16), dim3(256), 0, stream>>>(audio, gt, Sg);

    if (ws_size >= SG_BYTES + CUR_BYTES) {
        float* cur2 = (float*)((char*)d_ws + SG_BYTES);
        snnB1<<<dim3(B_, 2), dim3(1024), 0, stream>>>(Sg, Wb, cur2);
        snnB2<<<dim3(B_), dim3(1024), 0, stream>>>(cur2, Wic, Wac, (float*)d_out);
    } else {
        snnB<<<dim3(B_), dim3(TB_), 0, stream>>>(Sg, Wb, Wic, Wac, (float*)d_out);
    }
}